// Round 7
// baseline (1236.452 us; speedup 1.0000x reference)
//
#include <hip/hip_runtime.h>

#define NN 100000
#define NE 1600000
#define NLB 128            // chunks (k_lsort blocks)
#define CHUNK (NE / NLB)   // 12500 edges per chunk
#define NB 196             // dst buckets (dst >> 9), 196*512 >= NN
#define BN 512             // nodes per bucket

// ============================================ pass 1: block-local bucket sort
// Sort each chunk's edges by dst-bucket into the chunk's private region of
// `pairs`, packing (local_node<<17 | src) into one int (9+17 bits; src<2^17).
__global__ __launch_bounds__(256) void k_lsort(const int* __restrict__ src,
                                               const int* __restrict__ dst,
                                               int* __restrict__ pairs,
                                               int* __restrict__ tstart,
                                               int* __restrict__ tcnt) {
    __shared__ int cnt[NB];
    __shared__ int sc[256];
    __shared__ int cur[NB];
    int tid = threadIdx.x, blk = blockIdx.x;
    int e0 = blk * CHUNK;
    for (int i = tid; i < NB; i += 256) cnt[i] = 0;
    __syncthreads();
    for (int i = tid; i < CHUNK; i += 256) atomicAdd(&cnt[dst[e0 + i] >> 9], 1);
    __syncthreads();
    sc[tid] = (tid < NB) ? cnt[tid] : 0;
    __syncthreads();
    for (int off = 1; off < 256; off <<= 1) {
        int v = (tid >= off) ? sc[tid - off] : 0;
        __syncthreads();
        sc[tid] += v;
        __syncthreads();
    }
    if (tid < NB) {
        int excl = sc[tid] - cnt[tid];
        cur[tid] = excl;
        tstart[blk * NB + tid] = excl;          // chunk-relative
        tcnt[blk * NB + tid]   = cnt[tid];
    }
    __syncthreads();
    for (int i = tid; i < CHUNK; i += 256) {
        int d = dst[e0 + i], s = src[e0 + i];
        int p = atomicAdd(&cur[d >> 9], 1);
        pairs[e0 + p] = ((d & (BN - 1)) << 17) | s;
    }
}

// ==================== bucket aggregation over a 16-feature slice (32 KB LDS)
// Grid = NB * (ZW/16). Block handles bucket b = blockIdx/NS, features
// [fs, fs+16). Wave = 4 edge-groups x 16 lanes. Each 16-lane group loads the
// SAME pairs[st+i] address (HW broadcast, one transaction) -- no shfl.
// Group g processes edge indices i === g (mod 4); provably exactly-once.
template <int ZW>
__global__ __launch_bounds__(1024) void k_agg(const int* __restrict__ pairs,
                                              const int* __restrict__ tstart,
                                              const int* __restrict__ tcnt,
                                              const float* __restrict__ z,
                                              float* __restrict__ agg) {
    __shared__ float acc[BN * 16];   // 32 KB
    const int NS = ZW / 16;
    int b  = blockIdx.x / NS;
    int fs = (blockIdx.x % NS) * 16;
    int tid = threadIdx.x;
    for (int i = tid; i < BN * 16 / 4; i += 1024) ((float4*)acc)[i] = make_float4(0, 0, 0, 0);
    __syncthreads();
    int wave = tid >> 6, lane = tid & 63;
    int g = lane >> 4;            // 0..3: edge group
    int f = lane & 15;
    for (int c = wave; c < NLB; c += 16) {
        int st  = c * CHUNK + tstart[c * NB + b];
        int len = tcnt[c * NB + b];
        int i = g;
        for (; i + 12 < len; i += 16) {
            int p0 = pairs[st + i];
            int p1 = pairs[st + i + 4];
            int p2 = pairs[st + i + 8];
            int p3 = pairs[st + i + 12];
            float v0 = z[(size_t)(p0 & 0x1FFFF) * ZW + fs + f];
            float v1 = z[(size_t)(p1 & 0x1FFFF) * ZW + fs + f];
            float v2 = z[(size_t)(p2 & 0x1FFFF) * ZW + fs + f];
            float v3 = z[(size_t)(p3 & 0x1FFFF) * ZW + fs + f];
            atomicAdd(&acc[(p0 >> 17) * 16 + f], v0);
            atomicAdd(&acc[(p1 >> 17) * 16 + f], v1);
            atomicAdd(&acc[(p2 >> 17) * 16 + f], v2);
            atomicAdd(&acc[(p3 >> 17) * 16 + f], v3);
        }
        for (; i < len; i += 4) {
            int p = pairs[st + i];
            float v = z[(size_t)(p & 0x1FFFF) * ZW + fs + f];
            atomicAdd(&acc[(p >> 17) * 16 + f], v);
        }
    }
    __syncthreads();
    // writeback: acc float4 i -> node i>>2, feature chunk (i&3)*4 of slice
    for (int i = tid; i < BN * 16 / 4; i += 1024) {
        int n = b * BN + (i >> 2);
        if (n < NN) *(float4*)&agg[(size_t)n * ZW + fs + (i & 3) * 4] = ((float4*)acc)[i];
    }
}

// ================================================================ z1 = x @ W1
__global__ __launch_bounds__(256) void k_lin1(const float* __restrict__ x,
                                              const float* __restrict__ W1,
                                              float* __restrict__ z1) {
    __shared__ float Ws[128 * 32];
    __shared__ float xs[32][129];
    for (int i = threadIdx.x; i < 1024; i += 256) {
        float4 w = ((const float4*)W1)[i];
        float* d = &Ws[i * 4];
        d[0] = w.x; d[1] = w.y; d[2] = w.z; d[3] = w.w;
    }
    int n_loc = threadIdx.x >> 3;
    int j0    = (threadIdx.x & 7) * 4;
    for (int base = blockIdx.x * 32; base < NN; base += gridDim.x * 32) {
        __syncthreads();
        for (int t = threadIdx.x; t < 1024; t += 256) {
            int n = t >> 5, c = t & 31;
            float4 v = ((const float4*)(x + (size_t)(base + n) * 128))[c];
            float* d = &xs[n][c * 4];
            d[0] = v.x; d[1] = v.y; d[2] = v.z; d[3] = v.w;
        }
        __syncthreads();
        float a0 = 0.f, a1 = 0.f, a2 = 0.f, a3 = 0.f;
        #pragma unroll 8
        for (int k = 0; k < 128; k++) {
            float xv = xs[n_loc][k];
            float4 w = *(const float4*)&Ws[k * 32 + j0];
            a0 = fmaf(xv, w.x, a0); a1 = fmaf(xv, w.y, a1);
            a2 = fmaf(xv, w.z, a2); a3 = fmaf(xv, w.w, a3);
        }
        *(float4*)&z1[(size_t)(base + n_loc) * 32 + j0] = make_float4(a0, a1, a2, a3);
    }
}

// --------------- fused: t = relu(z1+agg1+b1); h = relu(t@W2+b2); z2 = h@W3
__global__ __launch_bounds__(256) void k_mid(const float* __restrict__ z1,
                                             const float* __restrict__ agg1,
                                             const float* __restrict__ b1,
                                             const float* __restrict__ W2,
                                             const float* __restrict__ b2,
                                             const float* __restrict__ W3,
                                             float* __restrict__ z2) {
    __shared__ float W2s[32 * 64];
    __shared__ float W3s[64 * 64];
    __shared__ float ts[32][33];
    __shared__ float hs[32 * 68];
    __shared__ float b1s[32], b2s[64];
    for (int i = threadIdx.x; i < 512; i += 256) {
        float4 w = ((const float4*)W2)[i];
        float* d = &W2s[i * 4];
        d[0] = w.x; d[1] = w.y; d[2] = w.z; d[3] = w.w;
    }
    for (int i = threadIdx.x; i < 1024; i += 256) {
        float4 w = ((const float4*)W3)[i];
        float* d = &W3s[i * 4];
        d[0] = w.x; d[1] = w.y; d[2] = w.z; d[3] = w.w;
    }
    if (threadIdx.x < 32) b1s[threadIdx.x] = b1[threadIdx.x];
    if (threadIdx.x >= 64 && threadIdx.x < 128) b2s[threadIdx.x - 64] = b2[threadIdx.x - 64];
    int n2 = threadIdx.x >> 4;
    int j0 = (threadIdx.x & 15) * 4;
    int na = 2 * n2, nb = 2 * n2 + 1;
    for (int base = blockIdx.x * 32; base < NN; base += gridDim.x * 32) {
        __syncthreads();
        #pragma unroll
        for (int r = 0; r < 4; r++) {
            int idx = threadIdx.x + 256 * r;
            int n = idx >> 5, f = idx & 31;
            ts[n][f] = fmaxf(z1[(size_t)base * 32 + idx] + agg1[(size_t)base * 32 + idx] + b1s[f], 0.f);
        }
        __syncthreads();
        {
            float a00=0,a01=0,a02=0,a03=0,a10=0,a11=0,a12=0,a13=0;
            #pragma unroll 8
            for (int k = 0; k < 32; k++) {
                float t0 = ts[na][k], t1 = ts[nb][k];
                float4 w = *(const float4*)&W2s[k * 64 + j0];
                a00=fmaf(t0,w.x,a00); a01=fmaf(t0,w.y,a01); a02=fmaf(t0,w.z,a02); a03=fmaf(t0,w.w,a03);
                a10=fmaf(t1,w.x,a10); a11=fmaf(t1,w.y,a11); a12=fmaf(t1,w.z,a12); a13=fmaf(t1,w.w,a13);
            }
            *(float4*)&hs[na * 68 + j0] = make_float4(fmaxf(a00+b2s[j0],0.f), fmaxf(a01+b2s[j0+1],0.f),
                                                      fmaxf(a02+b2s[j0+2],0.f), fmaxf(a03+b2s[j0+3],0.f));
            *(float4*)&hs[nb * 68 + j0] = make_float4(fmaxf(a10+b2s[j0],0.f), fmaxf(a11+b2s[j0+1],0.f),
                                                      fmaxf(a12+b2s[j0+2],0.f), fmaxf(a13+b2s[j0+3],0.f));
        }
        __syncthreads();
        {
            float a00=0,a01=0,a02=0,a03=0,a10=0,a11=0,a12=0,a13=0;
            #pragma unroll 8
            for (int k = 0; k < 64; k++) {
                float h0 = hs[na * 68 + k], h1 = hs[nb * 68 + k];
                float4 w = *(const float4*)&W3s[k * 64 + j0];
                a00=fmaf(h0,w.x,a00); a01=fmaf(h0,w.y,a01); a02=fmaf(h0,w.z,a02); a03=fmaf(h0,w.w,a03);
                a10=fmaf(h1,w.x,a10); a11=fmaf(h1,w.y,a11); a12=fmaf(h1,w.z,a12); a13=fmaf(h1,w.w,a13);
            }
            *(float4*)&z2[(size_t)(base + na) * 64 + j0] = make_float4(a00,a01,a02,a03);
            *(float4*)&z2[(size_t)(base + nb) * 64 + j0] = make_float4(a10,a11,a12,a13);
        }
    }
}

// --------- final: u = relu(z2+agg2+b3); out = relu(u@W4+b4) -> f32 + pooled
__global__ __launch_bounds__(256) void k_final(const float* __restrict__ z2,
                                               const float* __restrict__ agg2,
                                               const float* __restrict__ b3,
                                               const float* __restrict__ W4,
                                               const float* __restrict__ b4,
                                               float* __restrict__ out,
                                               float* __restrict__ gpool) {
    __shared__ float W4s[64 * 64];
    __shared__ float us[32 * 68];
    __shared__ float b3s[64], b4s[64], pool[64];
    for (int i = threadIdx.x; i < 1024; i += 256) {
        float4 w = ((const float4*)W4)[i];
        float* d = &W4s[i * 4];
        d[0] = w.x; d[1] = w.y; d[2] = w.z; d[3] = w.w;
    }
    if (threadIdx.x < 64) { b3s[threadIdx.x] = b3[threadIdx.x]; pool[threadIdx.x] = 0.f; }
    if (threadIdx.x >= 64 && threadIdx.x < 128) b4s[threadIdx.x - 64] = b4[threadIdx.x - 64];
    int n2 = threadIdx.x >> 4;
    int j0 = (threadIdx.x & 15) * 4;
    int na = 2 * n2, nb = 2 * n2 + 1;
    float p0 = 0.f, p1 = 0.f, p2 = 0.f, p3 = 0.f;
    for (int base = blockIdx.x * 32; base < NN; base += gridDim.x * 32) {
        __syncthreads();
        #pragma unroll
        for (int r = 0; r < 8; r++) {
            int idx = threadIdx.x + 256 * r;
            int n = idx >> 6, f = idx & 63;
            us[n * 68 + f] = fmaxf(z2[(size_t)base * 64 + idx] + agg2[(size_t)base * 64 + idx] + b3s[f], 0.f);
        }
        __syncthreads();
        float a00=0,a01=0,a02=0,a03=0,a10=0,a11=0,a12=0,a13=0;
        #pragma unroll 8
        for (int k = 0; k < 64; k++) {
            float u0 = us[na * 68 + k], u1 = us[nb * 68 + k];
            float4 w = *(const float4*)&W4s[k * 64 + j0];
            a00=fmaf(u0,w.x,a00); a01=fmaf(u0,w.y,a01); a02=fmaf(u0,w.z,a02); a03=fmaf(u0,w.w,a03);
            a10=fmaf(u1,w.x,a10); a11=fmaf(u1,w.y,a11); a12=fmaf(u1,w.z,a12); a13=fmaf(u1,w.w,a13);
        }
        float v00=fmaxf(a00+b4s[j0],0.f), v01=fmaxf(a01+b4s[j0+1],0.f);
        float v02=fmaxf(a02+b4s[j0+2],0.f), v03=fmaxf(a03+b4s[j0+3],0.f);
        float v10=fmaxf(a10+b4s[j0],0.f), v11=fmaxf(a11+b4s[j0+1],0.f);
        float v12=fmaxf(a12+b4s[j0+2],0.f), v13=fmaxf(a13+b4s[j0+3],0.f);
        *(float4*)&out[(size_t)(base + na) * 64 + j0] = make_float4(v00, v01, v02, v03);
        *(float4*)&out[(size_t)(base + nb) * 64 + j0] = make_float4(v10, v11, v12, v13);
        p0 += v00 + v10; p1 += v01 + v11; p2 += v02 + v12; p3 += v03 + v13;
    }
    __syncthreads();
    atomicAdd(&pool[j0 + 0], p0);
    atomicAdd(&pool[j0 + 1], p1);
    atomicAdd(&pool[j0 + 2], p2);
    atomicAdd(&pool[j0 + 3], p3);
    __syncthreads();
    if (threadIdx.x < 64) unsafeAtomicAdd(&gpool[threadIdx.x], pool[threadIdx.x]);
}

__global__ void k_pool(const float* __restrict__ gpool, float* __restrict__ out) {
    int t = threadIdx.x;
    if (t < 64) out[(size_t)NN * 64 + t] = gpool[t] * (1.0f / NN);
}

extern "C" void kernel_launch(void* const* d_in, const int* in_sizes, int n_in,
                              void* d_out, int out_size, void* d_ws, size_t ws_size,
                              hipStream_t stream) {
    const float* x  = (const float*)d_in[0];
    const int*   ei = (const int*)d_in[1];
    const float* W1 = (const float*)d_in[3];
    const float* b1 = (const float*)d_in[4];
    const float* W2 = (const float*)d_in[5];
    const float* b2 = (const float*)d_in[6];
    const float* W3 = (const float*)d_in[7];
    const float* b3 = (const float*)d_in[8];
    const float* W4 = (const float*)d_in[9];
    const float* b4 = (const float*)d_in[10];
    float* out = (float*)d_out;

    // ws (4B units): tstart[128*196] tcnt[128*196] gpool[64] pairs[NE]
    //   f32: z1[NN*32] agg1[NN*32] z2[NN*64]; agg2 aliases z1+agg1.
    //   total ~57.8 MB
    int*   ip     = (int*)d_ws;
    int*   tstart = ip;                         // 25088
    int*   tcnt   = ip + NLB * NB;              // 25088
    float* gpool  = (float*)(ip + 2 * NLB * NB);// 64
    int*   pairs  = ip + 2 * NLB * NB + 64;     // NE (packed edges; lives to k_agg<64>)
    float* fp     = (float*)(pairs + NE);
    float* z1     = fp;                         // NN*32
    float* agg1   = fp + (size_t)NN * 32;       // NN*32
    float* agg2   = fp;                         // alias z1+agg1 (dead after k_mid)
    float* z2     = fp + (size_t)NN * 64;       // NN*64
    const int* src = ei;
    const int* dst = ei + NE;

    hipMemsetAsync(gpool, 0, 64 * sizeof(float), stream);
    k_lsort<<<NLB, 256, 0, stream>>>(src, dst, pairs, tstart, tcnt);
    k_lin1<<<1024, 256, 0, stream>>>(x, W1, z1);
    k_agg<32><<<NB * 2, 1024, 0, stream>>>(pairs, tstart, tcnt, z1, agg1);
    k_mid<<<1024, 256, 0, stream>>>(z1, agg1, b1, W2, b2, W3, z2);
    k_agg<64><<<NB * 4, 1024, 0, stream>>>(pairs, tstart, tcnt, z2, agg2);
    k_final<<<1024, 256, 0, stream>>>(z2, agg2, b3, W4, b4, out, gpool);
    k_pool<<<1, 64, 0, stream>>>(gpool, out);
}

// Round 8
// 382.888 us; speedup vs baseline: 3.2293x; 3.2293x over previous
//
#include <hip/hip_runtime.h>

#define NN 100000
#define NE 1600000
#define NLB 128            // chunks (k_lsort blocks)
#define CHUNK (NE / NLB)   // 12500 edges per chunk
#define NB 196             // dst buckets (dst >> 9), 196*512 >= NN
#define BN 512             // nodes per bucket

// ============================================ pass 1: block-local bucket sort
// (verbatim from R7 — validated). Packs (local_node<<17 | src); src < 2^17.
__global__ __launch_bounds__(256) void k_lsort(const int* __restrict__ src,
                                               const int* __restrict__ dst,
                                               int* __restrict__ pairs,
                                               int* __restrict__ tstart,
                                               int* __restrict__ tcnt,
                                               int* __restrict__ btot) {
    __shared__ int cnt[NB];
    __shared__ int sc[256];
    __shared__ int cur[NB];
    int tid = threadIdx.x, blk = blockIdx.x;
    int e0 = blk * CHUNK;
    for (int i = tid; i < NB; i += 256) cnt[i] = 0;
    __syncthreads();
    for (int i = tid; i < CHUNK; i += 256) atomicAdd(&cnt[dst[e0 + i] >> 9], 1);
    __syncthreads();
    sc[tid] = (tid < NB) ? cnt[tid] : 0;
    __syncthreads();
    for (int off = 1; off < 256; off <<= 1) {
        int v = (tid >= off) ? sc[tid - off] : 0;
        __syncthreads();
        sc[tid] += v;
        __syncthreads();
    }
    if (tid < NB) {
        int excl = sc[tid] - cnt[tid];
        cur[tid] = excl;
        tstart[blk * NB + tid] = excl;          // chunk-relative
        tcnt[blk * NB + tid]   = cnt[tid];
        atomicAdd(&btot[tid], cnt[tid]);
    }
    __syncthreads();
    for (int i = tid; i < CHUNK; i += 256) {
        int d = dst[e0 + i], s = src[e0 + i];
        int p = atomicAdd(&cur[d >> 9], 1);
        pairs[e0 + p] = ((d & (BN - 1)) << 17) | s;
    }
}

// ============================= pass 2: per-bucket CSR via wave segment-walks
// 196 blocks x 1024 threads. Wave w walks segments w, w+16, ... with
// coalesced 64-lane reads. No binary search, no dependent-LDS chains.
__global__ __launch_bounds__(1024) void k_build(const int* __restrict__ pairs,
                                                const int* __restrict__ tstart,
                                                const int* __restrict__ tcnt,
                                                const int* __restrict__ btot,
                                                int* __restrict__ csr,
                                                int* __restrict__ row,
                                                int* __restrict__ rend) {
    __shared__ int segS[NLB], segL[NLB];
    __shared__ int ncnt[BN];
    __shared__ int nbase[BN + 1];
    __shared__ int sc[256];
    __shared__ int sc2[256];
    __shared__ int base_s;
    int tid = threadIdx.x, b = blockIdx.x;

    // bucket base = exclusive prefix of btot (scan in threads 0..255)
    if (tid < 256) sc2[tid] = (tid < NB) ? btot[tid] : 0;
    __syncthreads();
    for (int off = 1; off < 256; off <<= 1) {
        int v = 0;
        if (tid < 256 && tid >= off) v = sc2[tid - off];
        __syncthreads();
        if (tid < 256) sc2[tid] += v;
        __syncthreads();
    }
    if (tid == 0) base_s = (b == 0) ? 0 : sc2[b - 1];
    // segment tables
    if (tid < NLB) {
        segS[tid] = tid * CHUNK + tstart[tid * NB + b];
        segL[tid] = tcnt[tid * NB + b];
    }
    for (int i = tid; i < BN; i += 1024) ncnt[i] = 0;
    __syncthreads();

    int wave = tid >> 6, lane = tid & 63;
    // count phase: coalesced segment walks
    for (int s = wave; s < NLB; s += 16) {
        int st = segS[s], len = segL[s];
        for (int i = lane; i < len; i += 64)
            atomicAdd(&ncnt[pairs[st + i] >> 17], 1);
    }
    __syncthreads();

    // scan 512 counts: threads 0..255 handle 2 elements each
    int c0 = 0, c1 = 0, tsum = 0;
    if (tid < 256) { c0 = ncnt[2 * tid]; c1 = ncnt[2 * tid + 1]; tsum = c0 + c1; sc[tid] = tsum; }
    __syncthreads();
    for (int off = 1; off < 256; off <<= 1) {
        int v = 0;
        if (tid < 256 && tid >= off) v = sc[tid - off];
        __syncthreads();
        if (tid < 256) sc[tid] += v;
        __syncthreads();
    }
    if (tid < 256) {
        int excl = sc[tid] - tsum;
        nbase[2 * tid]     = excl;
        nbase[2 * tid + 1] = excl + c0;
        if (tid == 255) nbase[BN] = sc[255];
    }
    __syncthreads();

    int base = base_s;
    // row/rend + reset cursors
    if (tid < BN) {
        int n = b * BN + tid;
        if (n < NN) { row[n] = base + nbase[tid]; rend[n] = base + nbase[tid + 1]; }
        ncnt[tid] = 0;
    }
    __syncthreads();

    // place phase: coalesced reads, csr window ~64KB -> L2 write-combined
    for (int s = wave; s < NLB; s += 16) {
        int st = segS[s], len = segL[s];
        for (int i = lane; i < len; i += 64) {
            int p = pairs[st + i];
            int ln = p >> 17;
            int pos = atomicAdd(&ncnt[ln], 1);
            csr[base + nbase[ln] + pos] = p & 0x1FFFF;
        }
    }
}

// ================================================================ gathers
// (verbatim from R3/R4 — validated)
__global__ __launch_bounds__(256) void k_gather32(const int* __restrict__ row,
                                                  const int* __restrict__ rend,
                                                  const int* __restrict__ csr,
                                                  const float* __restrict__ z,
                                                  float* __restrict__ agg) {
    int n = blockIdx.x * 8 + (threadIdx.x >> 5);
    int f = threadIdx.x & 31;
    int j = row[n], e = rend[n];
    float a0 = 0.f, a1 = 0.f, a2 = 0.f, a3 = 0.f;
    for (; j + 3 < e; j += 4) {
        int i0 = csr[j], i1 = csr[j + 1], i2 = csr[j + 2], i3 = csr[j + 3];
        a0 += z[(size_t)i0 * 32 + f];
        a1 += z[(size_t)i1 * 32 + f];
        a2 += z[(size_t)i2 * 32 + f];
        a3 += z[(size_t)i3 * 32 + f];
    }
    for (; j < e; j++) a0 += z[(size_t)csr[j] * 32 + f];
    agg[(size_t)n * 32 + f] = (a0 + a1) + (a2 + a3);
}

__global__ __launch_bounds__(256) void k_gather64(const int* __restrict__ row,
                                                  const int* __restrict__ rend,
                                                  const int* __restrict__ csr,
                                                  const float* __restrict__ z,
                                                  float* __restrict__ agg) {
    int n = blockIdx.x * 4 + (threadIdx.x >> 6);
    int f = threadIdx.x & 63;
    int j = row[n], e = rend[n];
    float a0 = 0.f, a1 = 0.f, a2 = 0.f, a3 = 0.f;
    for (; j + 3 < e; j += 4) {
        int i0 = csr[j], i1 = csr[j + 1], i2 = csr[j + 2], i3 = csr[j + 3];
        a0 += z[(size_t)i0 * 64 + f];
        a1 += z[(size_t)i1 * 64 + f];
        a2 += z[(size_t)i2 * 64 + f];
        a3 += z[(size_t)i3 * 64 + f];
    }
    for (; j < e; j++) a0 += z[(size_t)csr[j] * 64 + f];
    agg[(size_t)n * 64 + f] = (a0 + a1) + (a2 + a3);
}

// ================================================================ z1 = x @ W1
__global__ __launch_bounds__(256) void k_lin1(const float* __restrict__ x,
                                              const float* __restrict__ W1,
                                              float* __restrict__ z1) {
    __shared__ float Ws[128 * 32];
    __shared__ float xs[32][129];
    for (int i = threadIdx.x; i < 1024; i += 256) {
        float4 w = ((const float4*)W1)[i];
        float* d = &Ws[i * 4];
        d[0] = w.x; d[1] = w.y; d[2] = w.z; d[3] = w.w;
    }
    int n_loc = threadIdx.x >> 3;
    int j0    = (threadIdx.x & 7) * 4;
    for (int base = blockIdx.x * 32; base < NN; base += gridDim.x * 32) {
        __syncthreads();
        for (int t = threadIdx.x; t < 1024; t += 256) {
            int n = t >> 5, c = t & 31;
            float4 v = ((const float4*)(x + (size_t)(base + n) * 128))[c];
            float* d = &xs[n][c * 4];
            d[0] = v.x; d[1] = v.y; d[2] = v.z; d[3] = v.w;
        }
        __syncthreads();
        float a0 = 0.f, a1 = 0.f, a2 = 0.f, a3 = 0.f;
        #pragma unroll 8
        for (int k = 0; k < 128; k++) {
            float xv = xs[n_loc][k];
            float4 w = *(const float4*)&Ws[k * 32 + j0];
            a0 = fmaf(xv, w.x, a0); a1 = fmaf(xv, w.y, a1);
            a2 = fmaf(xv, w.z, a2); a3 = fmaf(xv, w.w, a3);
        }
        *(float4*)&z1[(size_t)(base + n_loc) * 32 + j0] = make_float4(a0, a1, a2, a3);
    }
}

// --------------- fused: t = relu(z1+agg1+b1); h = relu(t@W2+b2); z2 = h@W3
__global__ __launch_bounds__(256) void k_mid(const float* __restrict__ z1,
                                             const float* __restrict__ agg1,
                                             const float* __restrict__ b1,
                                             const float* __restrict__ W2,
                                             const float* __restrict__ b2,
                                             const float* __restrict__ W3,
                                             float* __restrict__ z2) {
    __shared__ float W2s[32 * 64];
    __shared__ float W3s[64 * 64];
    __shared__ float ts[32][33];
    __shared__ float hs[32 * 68];
    __shared__ float b1s[32], b2s[64];
    for (int i = threadIdx.x; i < 512; i += 256) {
        float4 w = ((const float4*)W2)[i];
        float* d = &W2s[i * 4];
        d[0] = w.x; d[1] = w.y; d[2] = w.z; d[3] = w.w;
    }
    for (int i = threadIdx.x; i < 1024; i += 256) {
        float4 w = ((const float4*)W3)[i];
        float* d = &W3s[i * 4];
        d[0] = w.x; d[1] = w.y; d[2] = w.z; d[3] = w.w;
    }
    if (threadIdx.x < 32) b1s[threadIdx.x] = b1[threadIdx.x];
    if (threadIdx.x >= 64 && threadIdx.x < 128) b2s[threadIdx.x - 64] = b2[threadIdx.x - 64];
    int n2 = threadIdx.x >> 4;
    int j0 = (threadIdx.x & 15) * 4;
    int na = 2 * n2, nb = 2 * n2 + 1;
    for (int base = blockIdx.x * 32; base < NN; base += gridDim.x * 32) {
        __syncthreads();
        #pragma unroll
        for (int r = 0; r < 4; r++) {
            int idx = threadIdx.x + 256 * r;
            int n = idx >> 5, f = idx & 31;
            ts[n][f] = fmaxf(z1[(size_t)base * 32 + idx] + agg1[(size_t)base * 32 + idx] + b1s[f], 0.f);
        }
        __syncthreads();
        {
            float a00=0,a01=0,a02=0,a03=0,a10=0,a11=0,a12=0,a13=0;
            #pragma unroll 8
            for (int k = 0; k < 32; k++) {
                float t0 = ts[na][k], t1 = ts[nb][k];
                float4 w = *(const float4*)&W2s[k * 64 + j0];
                a00=fmaf(t0,w.x,a00); a01=fmaf(t0,w.y,a01); a02=fmaf(t0,w.z,a02); a03=fmaf(t0,w.w,a03);
                a10=fmaf(t1,w.x,a10); a11=fmaf(t1,w.y,a11); a12=fmaf(t1,w.z,a12); a13=fmaf(t1,w.w,a13);
            }
            *(float4*)&hs[na * 68 + j0] = make_float4(fmaxf(a00+b2s[j0],0.f), fmaxf(a01+b2s[j0+1],0.f),
                                                      fmaxf(a02+b2s[j0+2],0.f), fmaxf(a03+b2s[j0+3],0.f));
            *(float4*)&hs[nb * 68 + j0] = make_float4(fmaxf(a10+b2s[j0],0.f), fmaxf(a11+b2s[j0+1],0.f),
                                                      fmaxf(a12+b2s[j0+2],0.f), fmaxf(a13+b2s[j0+3],0.f));
        }
        __syncthreads();
        {
            float a00=0,a01=0,a02=0,a03=0,a10=0,a11=0,a12=0,a13=0;
            #pragma unroll 8
            for (int k = 0; k < 64; k++) {
                float h0 = hs[na * 68 + k], h1 = hs[nb * 68 + k];
                float4 w = *(const float4*)&W3s[k * 64 + j0];
                a00=fmaf(h0,w.x,a00); a01=fmaf(h0,w.y,a01); a02=fmaf(h0,w.z,a02); a03=fmaf(h0,w.w,a03);
                a10=fmaf(h1,w.x,a10); a11=fmaf(h1,w.y,a11); a12=fmaf(h1,w.z,a12); a13=fmaf(h1,w.w,a13);
            }
            *(float4*)&z2[(size_t)(base + na) * 64 + j0] = make_float4(a00,a01,a02,a03);
            *(float4*)&z2[(size_t)(base + nb) * 64 + j0] = make_float4(a10,a11,a12,a13);
        }
    }
}

// --------- final: u = relu(z2+agg2+b3); out = relu(u@W4+b4) -> f32 + pooled
__global__ __launch_bounds__(256) void k_final(const float* __restrict__ z2,
                                               const float* __restrict__ agg2,
                                               const float* __restrict__ b3,
                                               const float* __restrict__ W4,
                                               const float* __restrict__ b4,
                                               float* __restrict__ out,
                                               float* __restrict__ gpool) {
    __shared__ float W4s[64 * 64];
    __shared__ float us[32 * 68];
    __shared__ float b3s[64], b4s[64], pool[64];
    for (int i = threadIdx.x; i < 1024; i += 256) {
        float4 w = ((const float4*)W4)[i];
        float* d = &W4s[i * 4];
        d[0] = w.x; d[1] = w.y; d[2] = w.z; d[3] = w.w;
    }
    if (threadIdx.x < 64) { b3s[threadIdx.x] = b3[threadIdx.x]; pool[threadIdx.x] = 0.f; }
    if (threadIdx.x >= 64 && threadIdx.x < 128) b4s[threadIdx.x - 64] = b4[threadIdx.x - 64];
    int n2 = threadIdx.x >> 4;
    int j0 = (threadIdx.x & 15) * 4;
    int na = 2 * n2, nb = 2 * n2 + 1;
    float p0 = 0.f, p1 = 0.f, p2 = 0.f, p3 = 0.f;
    for (int base = blockIdx.x * 32; base < NN; base += gridDim.x * 32) {
        __syncthreads();
        #pragma unroll
        for (int r = 0; r < 8; r++) {
            int idx = threadIdx.x + 256 * r;
            int n = idx >> 6, f = idx & 63;
            us[n * 68 + f] = fmaxf(z2[(size_t)base * 64 + idx] + agg2[(size_t)base * 64 + idx] + b3s[f], 0.f);
        }
        __syncthreads();
        float a00=0,a01=0,a02=0,a03=0,a10=0,a11=0,a12=0,a13=0;
        #pragma unroll 8
        for (int k = 0; k < 64; k++) {
            float u0 = us[na * 68 + k], u1 = us[nb * 68 + k];
            float4 w = *(const float4*)&W4s[k * 64 + j0];
            a00=fmaf(u0,w.x,a00); a01=fmaf(u0,w.y,a01); a02=fmaf(u0,w.z,a02); a03=fmaf(u0,w.w,a03);
            a10=fmaf(u1,w.x,a10); a11=fmaf(u1,w.y,a11); a12=fmaf(u1,w.z,a12); a13=fmaf(u1,w.w,a13);
        }
        float v00=fmaxf(a00+b4s[j0],0.f), v01=fmaxf(a01+b4s[j0+1],0.f);
        float v02=fmaxf(a02+b4s[j0+2],0.f), v03=fmaxf(a03+b4s[j0+3],0.f);
        float v10=fmaxf(a10+b4s[j0],0.f), v11=fmaxf(a11+b4s[j0+1],0.f);
        float v12=fmaxf(a12+b4s[j0+2],0.f), v13=fmaxf(a13+b4s[j0+3],0.f);
        *(float4*)&out[(size_t)(base + na) * 64 + j0] = make_float4(v00, v01, v02, v03);
        *(float4*)&out[(size_t)(base + nb) * 64 + j0] = make_float4(v10, v11, v12, v13);
        p0 += v00 + v10; p1 += v01 + v11; p2 += v02 + v12; p3 += v03 + v13;
    }
    __syncthreads();
    atomicAdd(&pool[j0 + 0], p0);
    atomicAdd(&pool[j0 + 1], p1);
    atomicAdd(&pool[j0 + 2], p2);
    atomicAdd(&pool[j0 + 3], p3);
    __syncthreads();
    if (threadIdx.x < 64) unsafeAtomicAdd(&gpool[threadIdx.x], pool[threadIdx.x]);
}

__global__ void k_pool(const float* __restrict__ gpool, float* __restrict__ out) {
    int t = threadIdx.x;
    if (t < 64) out[(size_t)NN * 64 + t] = gpool[t] * (1.0f / NN);
}

extern "C" void kernel_launch(void* const* d_in, const int* in_sizes, int n_in,
                              void* d_out, int out_size, void* d_ws, size_t ws_size,
                              hipStream_t stream) {
    const float* x  = (const float*)d_in[0];
    const int*   ei = (const int*)d_in[1];
    const float* W1 = (const float*)d_in[3];
    const float* b1 = (const float*)d_in[4];
    const float* W2 = (const float*)d_in[5];
    const float* b2 = (const float*)d_in[6];
    const float* W3 = (const float*)d_in[7];
    const float* b3 = (const float*)d_in[8];
    const float* W4 = (const float*)d_in[9];
    const float* b4 = (const float*)d_in[10];
    float* out = (float*)d_out;

    // ws (4B units): tstart[128*196] tcnt[128*196] btot[196] gpool[64]
    //   row[NN] rend[NN] csr[NE]
    //   f32: z1[NN*32] agg1[NN*32] z2[NN*64]
    //   pairs[NE] aliases z2 (dead before k_mid writes z2);
    //   agg2 aliases z1+agg1 (dead after k_mid).   total ~59 MB
    int*   ip     = (int*)d_ws;
    int*   tstart = ip;                          // 25088
    int*   tcnt   = ip + NLB * NB;               // 25088
    int*   btot   = ip + 2 * NLB * NB;           // 196
    float* gpool  = (float*)(ip + 2 * NLB * NB + 196);  // 64
    int*   row    = ip + 2 * NLB * NB + 260;     // NN
    int*   rend   = row + NN;                    // NN
    int*   csr    = rend + NN;                   // NE
    float* fp     = (float*)(csr + NE + 32);
    float* z1     = fp;                          // NN*32
    float* agg1   = fp + (size_t)NN * 32;        // NN*32
    float* agg2   = fp;                          // alias z1+agg1
    float* z2     = fp + (size_t)NN * 64;        // NN*64
    int*   pairs  = (int*)z2;                    // alias z2 (NE ints < NN*64 f32)
    const int* src = ei;
    const int* dst = ei + NE;

    hipMemsetAsync(btot, 0, (196 + 64) * sizeof(int), stream);  // btot + gpool
    k_lsort<<<NLB, 256, 0, stream>>>(src, dst, pairs, tstart, tcnt, btot);
    k_build<<<NB, 1024, 0, stream>>>(pairs, tstart, tcnt, btot, csr, row, rend);
    k_lin1<<<1024, 256, 0, stream>>>(x, W1, z1);
    k_gather32<<<NN / 8, 256, 0, stream>>>(row, rend, csr, z1, agg1);
    k_mid<<<1024, 256, 0, stream>>>(z1, agg1, b1, W2, b2, W3, z2);
    k_gather64<<<NN / 4, 256, 0, stream>>>(row, rend, csr, z2, agg2);
    k_final<<<1024, 256, 0, stream>>>(z2, agg2, b3, W4, b4, out, gpool);
    k_pool<<<1, 64, 0, stream>>>(gpool, out);
}

// Round 9
// 352.645 us; speedup vs baseline: 3.5062x; 1.0858x over previous
//
#include <hip/hip_runtime.h>

#define NN 100000
#define NE 1600000
#define NLB 128            // chunks (k_lsort blocks)
#define CHUNK (NE / NLB)   // 12500 edges per chunk
#define NB 196             // dst buckets (dst >> 9), 196*512 >= NN
#define BN 512             // nodes per bucket

__device__ __forceinline__ float bf2f(unsigned short u) {
    return __uint_as_float(((unsigned int)u) << 16);
}
__device__ __forceinline__ unsigned short f2bf(float f) {
    unsigned int u = __float_as_uint(f);
    return (unsigned short)((u + 0x7FFFu + ((u >> 16) & 1u)) >> 16);
}

// ============================================ pass 1: block-local bucket sort
// (validated R7/R8) Packs (local_node<<17 | src); src < 2^17.
__global__ __launch_bounds__(256) void k_lsort(const int* __restrict__ src,
                                               const int* __restrict__ dst,
                                               int* __restrict__ pairs,
                                               int* __restrict__ tstart,
                                               int* __restrict__ tcnt,
                                               int* __restrict__ btot) {
    __shared__ int cnt[NB];
    __shared__ int sc[256];
    __shared__ int cur[NB];
    int tid = threadIdx.x, blk = blockIdx.x;
    int e0 = blk * CHUNK;
    for (int i = tid; i < NB; i += 256) cnt[i] = 0;
    __syncthreads();
    for (int i = tid; i < CHUNK; i += 256) atomicAdd(&cnt[dst[e0 + i] >> 9], 1);
    __syncthreads();
    sc[tid] = (tid < NB) ? cnt[tid] : 0;
    __syncthreads();
    for (int off = 1; off < 256; off <<= 1) {
        int v = (tid >= off) ? sc[tid - off] : 0;
        __syncthreads();
        sc[tid] += v;
        __syncthreads();
    }
    if (tid < NB) {
        int excl = sc[tid] - cnt[tid];
        cur[tid] = excl;
        tstart[blk * NB + tid] = excl;
        tcnt[blk * NB + tid]   = cnt[tid];
        atomicAdd(&btot[tid], cnt[tid]);
    }
    __syncthreads();
    for (int i = tid; i < CHUNK; i += 256) {
        int d = dst[e0 + i], s = src[e0 + i];
        int p = atomicAdd(&cur[d >> 9], 1);
        pairs[e0 + p] = ((d & (BN - 1)) << 17) | s;
    }
}

// ============================= pass 2: per-bucket CSR via wave segment-walks
// (validated R8)
__global__ __launch_bounds__(1024) void k_build(const int* __restrict__ pairs,
                                                const int* __restrict__ tstart,
                                                const int* __restrict__ tcnt,
                                                const int* __restrict__ btot,
                                                int* __restrict__ csr,
                                                int* __restrict__ row,
                                                int* __restrict__ rend) {
    __shared__ int segS[NLB], segL[NLB];
    __shared__ int ncnt[BN];
    __shared__ int nbase[BN + 1];
    __shared__ int sc[256];
    __shared__ int sc2[256];
    __shared__ int base_s;
    int tid = threadIdx.x, b = blockIdx.x;

    if (tid < 256) sc2[tid] = (tid < NB) ? btot[tid] : 0;
    __syncthreads();
    for (int off = 1; off < 256; off <<= 1) {
        int v = 0;
        if (tid < 256 && tid >= off) v = sc2[tid - off];
        __syncthreads();
        if (tid < 256) sc2[tid] += v;
        __syncthreads();
    }
    if (tid == 0) base_s = (b == 0) ? 0 : sc2[b - 1];
    if (tid < NLB) {
        segS[tid] = tid * CHUNK + tstart[tid * NB + b];
        segL[tid] = tcnt[tid * NB + b];
    }
    for (int i = tid; i < BN; i += 1024) ncnt[i] = 0;
    __syncthreads();

    int wave = tid >> 6, lane = tid & 63;
    for (int s = wave; s < NLB; s += 16) {
        int st = segS[s], len = segL[s];
        for (int i = lane; i < len; i += 64)
            atomicAdd(&ncnt[pairs[st + i] >> 17], 1);
    }
    __syncthreads();

    int c0 = 0, c1 = 0, tsum = 0;
    if (tid < 256) { c0 = ncnt[2 * tid]; c1 = ncnt[2 * tid + 1]; tsum = c0 + c1; sc[tid] = tsum; }
    __syncthreads();
    for (int off = 1; off < 256; off <<= 1) {
        int v = 0;
        if (tid < 256 && tid >= off) v = sc[tid - off];
        __syncthreads();
        if (tid < 256) sc[tid] += v;
        __syncthreads();
    }
    if (tid < 256) {
        int excl = sc[tid] - tsum;
        nbase[2 * tid]     = excl;
        nbase[2 * tid + 1] = excl + c0;
        if (tid == 255) nbase[BN] = sc[255];
    }
    __syncthreads();

    int base = base_s;
    if (tid < BN) {
        int n = b * BN + tid;
        if (n < NN) { row[n] = base + nbase[tid]; rend[n] = base + nbase[tid + 1]; }
        ncnt[tid] = 0;
    }
    __syncthreads();

    for (int s = wave; s < NLB; s += 16) {
        int st = segS[s], len = segL[s];
        for (int i = lane; i < len; i += 64) {
            int p = pairs[st + i];
            int ln = p >> 17;
            int pos = atomicAdd(&ncnt[ln], 1);
            csr[base + nbase[ln] + pos] = p & 0x1FFFF;
        }
    }
}

// ================================================================ gathers
// bf16 z rows, fp32 accumulate, fp32 agg out.
__global__ __launch_bounds__(256) void k_gather32(const int* __restrict__ row,
                                                  const int* __restrict__ rend,
                                                  const int* __restrict__ csr,
                                                  const unsigned short* __restrict__ z,
                                                  float* __restrict__ agg) {
    int n = blockIdx.x * 8 + (threadIdx.x >> 5);
    int f = threadIdx.x & 31;
    int j = row[n], e = rend[n];
    float a0 = 0.f, a1 = 0.f, a2 = 0.f, a3 = 0.f;
    for (; j + 3 < e; j += 4) {
        int i0 = csr[j], i1 = csr[j + 1], i2 = csr[j + 2], i3 = csr[j + 3];
        a0 += bf2f(z[(size_t)i0 * 32 + f]);
        a1 += bf2f(z[(size_t)i1 * 32 + f]);
        a2 += bf2f(z[(size_t)i2 * 32 + f]);
        a3 += bf2f(z[(size_t)i3 * 32 + f]);
    }
    for (; j < e; j++) a0 += bf2f(z[(size_t)csr[j] * 32 + f]);
    agg[(size_t)n * 32 + f] = (a0 + a1) + (a2 + a3);
}

__global__ __launch_bounds__(256) void k_gather64(const int* __restrict__ row,
                                                  const int* __restrict__ rend,
                                                  const int* __restrict__ csr,
                                                  const unsigned short* __restrict__ z,
                                                  float* __restrict__ agg) {
    int n = blockIdx.x * 4 + (threadIdx.x >> 6);
    int f = threadIdx.x & 63;
    int j = row[n], e = rend[n];
    float a0 = 0.f, a1 = 0.f, a2 = 0.f, a3 = 0.f;
    for (; j + 3 < e; j += 4) {
        int i0 = csr[j], i1 = csr[j + 1], i2 = csr[j + 2], i3 = csr[j + 3];
        a0 += bf2f(z[(size_t)i0 * 64 + f]);
        a1 += bf2f(z[(size_t)i1 * 64 + f]);
        a2 += bf2f(z[(size_t)i2 * 64 + f]);
        a3 += bf2f(z[(size_t)i3 * 64 + f]);
    }
    for (; j < e; j++) a0 += bf2f(z[(size_t)csr[j] * 64 + f]);
    agg[(size_t)n * 64 + f] = (a0 + a1) + (a2 + a3);
}

// ====================================================== z1 = x @ W1 (bf16 out)
__global__ __launch_bounds__(256) void k_lin1(const float* __restrict__ x,
                                              const float* __restrict__ W1,
                                              unsigned short* __restrict__ z1) {
    __shared__ float Ws[128 * 32];
    __shared__ float xs[32][129];
    for (int i = threadIdx.x; i < 1024; i += 256) {
        float4 w = ((const float4*)W1)[i];
        float* d = &Ws[i * 4];
        d[0] = w.x; d[1] = w.y; d[2] = w.z; d[3] = w.w;
    }
    int n_loc = threadIdx.x >> 3;
    int j0    = (threadIdx.x & 7) * 4;
    for (int base = blockIdx.x * 32; base < NN; base += gridDim.x * 32) {
        __syncthreads();
        for (int t = threadIdx.x; t < 1024; t += 256) {
            int n = t >> 5, c = t & 31;
            float4 v = ((const float4*)(x + (size_t)(base + n) * 128))[c];
            float* d = &xs[n][c * 4];
            d[0] = v.x; d[1] = v.y; d[2] = v.z; d[3] = v.w;
        }
        __syncthreads();
        float a0 = 0.f, a1 = 0.f, a2 = 0.f, a3 = 0.f;
        #pragma unroll 8
        for (int k = 0; k < 128; k++) {
            float xv = xs[n_loc][k];
            float4 w = *(const float4*)&Ws[k * 32 + j0];
            a0 = fmaf(xv, w.x, a0); a1 = fmaf(xv, w.y, a1);
            a2 = fmaf(xv, w.z, a2); a3 = fmaf(xv, w.w, a3);
        }
        ushort4 o = { f2bf(a0), f2bf(a1), f2bf(a2), f2bf(a3) };
        *(ushort4*)&z1[(size_t)(base + n_loc) * 32 + j0] = o;
    }
}

// --- fused: t = relu(z1+agg1+b1); h = relu(t@W2+b2); z2 = h@W3 (bf16 in/out)
__global__ __launch_bounds__(256) void k_mid(const unsigned short* __restrict__ z1,
                                             const float* __restrict__ agg1,
                                             const float* __restrict__ b1,
                                             const float* __restrict__ W2,
                                             const float* __restrict__ b2,
                                             const float* __restrict__ W3,
                                             unsigned short* __restrict__ z2) {
    __shared__ float W2s[32 * 64];
    __shared__ float W3s[64 * 64];
    __shared__ float ts[32][33];
    __shared__ float hs[32 * 68];
    __shared__ float b1s[32], b2s[64];
    for (int i = threadIdx.x; i < 512; i += 256) {
        float4 w = ((const float4*)W2)[i];
        float* d = &W2s[i * 4];
        d[0] = w.x; d[1] = w.y; d[2] = w.z; d[3] = w.w;
    }
    for (int i = threadIdx.x; i < 1024; i += 256) {
        float4 w = ((const float4*)W3)[i];
        float* d = &W3s[i * 4];
        d[0] = w.x; d[1] = w.y; d[2] = w.z; d[3] = w.w;
    }
    if (threadIdx.x < 32) b1s[threadIdx.x] = b1[threadIdx.x];
    if (threadIdx.x >= 64 && threadIdx.x < 128) b2s[threadIdx.x - 64] = b2[threadIdx.x - 64];
    int n2 = threadIdx.x >> 4;
    int j0 = (threadIdx.x & 15) * 4;
    int na = 2 * n2, nb = 2 * n2 + 1;
    for (int base = blockIdx.x * 32; base < NN; base += gridDim.x * 32) {
        __syncthreads();
        #pragma unroll
        for (int r = 0; r < 4; r++) {
            int idx = threadIdx.x + 256 * r;
            int n = idx >> 5, f = idx & 31;
            ts[n][f] = fmaxf(bf2f(z1[(size_t)base * 32 + idx]) + agg1[(size_t)base * 32 + idx] + b1s[f], 0.f);
        }
        __syncthreads();
        {
            float a00=0,a01=0,a02=0,a03=0,a10=0,a11=0,a12=0,a13=0;
            #pragma unroll 8
            for (int k = 0; k < 32; k++) {
                float t0 = ts[na][k], t1 = ts[nb][k];
                float4 w = *(const float4*)&W2s[k * 64 + j0];
                a00=fmaf(t0,w.x,a00); a01=fmaf(t0,w.y,a01); a02=fmaf(t0,w.z,a02); a03=fmaf(t0,w.w,a03);
                a10=fmaf(t1,w.x,a10); a11=fmaf(t1,w.y,a11); a12=fmaf(t1,w.z,a12); a13=fmaf(t1,w.w,a13);
            }
            *(float4*)&hs[na * 68 + j0] = make_float4(fmaxf(a00+b2s[j0],0.f), fmaxf(a01+b2s[j0+1],0.f),
                                                      fmaxf(a02+b2s[j0+2],0.f), fmaxf(a03+b2s[j0+3],0.f));
            *(float4*)&hs[nb * 68 + j0] = make_float4(fmaxf(a10+b2s[j0],0.f), fmaxf(a11+b2s[j0+1],0.f),
                                                      fmaxf(a12+b2s[j0+2],0.f), fmaxf(a13+b2s[j0+3],0.f));
        }
        __syncthreads();
        {
            float a00=0,a01=0,a02=0,a03=0,a10=0,a11=0,a12=0,a13=0;
            #pragma unroll 8
            for (int k = 0; k < 64; k++) {
                float h0 = hs[na * 68 + k], h1 = hs[nb * 68 + k];
                float4 w = *(const float4*)&W3s[k * 64 + j0];
                a00=fmaf(h0,w.x,a00); a01=fmaf(h0,w.y,a01); a02=fmaf(h0,w.z,a02); a03=fmaf(h0,w.w,a03);
                a10=fmaf(h1,w.x,a10); a11=fmaf(h1,w.y,a11); a12=fmaf(h1,w.z,a12); a13=fmaf(h1,w.w,a13);
            }
            ushort4 oa = { f2bf(a00), f2bf(a01), f2bf(a02), f2bf(a03) };
            ushort4 ob = { f2bf(a10), f2bf(a11), f2bf(a12), f2bf(a13) };
            *(ushort4*)&z2[(size_t)(base + na) * 64 + j0] = oa;
            *(ushort4*)&z2[(size_t)(base + nb) * 64 + j0] = ob;
        }
    }
}

// --------- final: u = relu(z2+agg2+b3); out = relu(u@W4+b4) -> f32 + pooled
__global__ __launch_bounds__(256) void k_final(const unsigned short* __restrict__ z2,
                                               const float* __restrict__ agg2,
                                               const float* __restrict__ b3,
                                               const float* __restrict__ W4,
                                               const float* __restrict__ b4,
                                               float* __restrict__ out,
                                               float* __restrict__ gpool) {
    __shared__ float W4s[64 * 64];
    __shared__ float us[32 * 68];
    __shared__ float b3s[64], b4s[64], pool[64];
    for (int i = threadIdx.x; i < 1024; i += 256) {
        float4 w = ((const float4*)W4)[i];
        float* d = &W4s[i * 4];
        d[0] = w.x; d[1] = w.y; d[2] = w.z; d[3] = w.w;
    }
    if (threadIdx.x < 64) { b3s[threadIdx.x] = b3[threadIdx.x]; pool[threadIdx.x] = 0.f; }
    if (threadIdx.x >= 64 && threadIdx.x < 128) b4s[threadIdx.x - 64] = b4[threadIdx.x - 64];
    int n2 = threadIdx.x >> 4;
    int j0 = (threadIdx.x & 15) * 4;
    int na = 2 * n2, nb = 2 * n2 + 1;
    float p0 = 0.f, p1 = 0.f, p2 = 0.f, p3 = 0.f;
    for (int base = blockIdx.x * 32; base < NN; base += gridDim.x * 32) {
        __syncthreads();
        #pragma unroll
        for (int r = 0; r < 8; r++) {
            int idx = threadIdx.x + 256 * r;
            int n = idx >> 6, f = idx & 63;
            us[n * 68 + f] = fmaxf(bf2f(z2[(size_t)base * 64 + idx]) + agg2[(size_t)base * 64 + idx] + b3s[f], 0.f);
        }
        __syncthreads();
        float a00=0,a01=0,a02=0,a03=0,a10=0,a11=0,a12=0,a13=0;
        #pragma unroll 8
        for (int k = 0; k < 64; k++) {
            float u0 = us[na * 68 + k], u1 = us[nb * 68 + k];
            float4 w = *(const float4*)&W4s[k * 64 + j0];
            a00=fmaf(u0,w.x,a00); a01=fmaf(u0,w.y,a01); a02=fmaf(u0,w.z,a02); a03=fmaf(u0,w.w,a03);
            a10=fmaf(u1,w.x,a10); a11=fmaf(u1,w.y,a11); a12=fmaf(u1,w.z,a12); a13=fmaf(u1,w.w,a13);
        }
        float v00=fmaxf(a00+b4s[j0],0.f), v01=fmaxf(a01+b4s[j0+1],0.f);
        float v02=fmaxf(a02+b4s[j0+2],0.f), v03=fmaxf(a03+b4s[j0+3],0.f);
        float v10=fmaxf(a10+b4s[j0],0.f), v11=fmaxf(a11+b4s[j0+1],0.f);
        float v12=fmaxf(a12+b4s[j0+2],0.f), v13=fmaxf(a13+b4s[j0+3],0.f);
        *(float4*)&out[(size_t)(base + na) * 64 + j0] = make_float4(v00, v01, v02, v03);
        *(float4*)&out[(size_t)(base + nb) * 64 + j0] = make_float4(v10, v11, v12, v13);
        p0 += v00 + v10; p1 += v01 + v11; p2 += v02 + v12; p3 += v03 + v13;
    }
    __syncthreads();
    atomicAdd(&pool[j0 + 0], p0);
    atomicAdd(&pool[j0 + 1], p1);
    atomicAdd(&pool[j0 + 2], p2);
    atomicAdd(&pool[j0 + 3], p3);
    __syncthreads();
    if (threadIdx.x < 64) unsafeAtomicAdd(&gpool[threadIdx.x], pool[threadIdx.x]);
}

__global__ void k_pool(const float* __restrict__ gpool, float* __restrict__ out) {
    int t = threadIdx.x;
    if (t < 64) out[(size_t)NN * 64 + t] = gpool[t] * (1.0f / NN);
}

extern "C" void kernel_launch(void* const* d_in, const int* in_sizes, int n_in,
                              void* d_out, int out_size, void* d_ws, size_t ws_size,
                              hipStream_t stream) {
    const float* x  = (const float*)d_in[0];
    const int*   ei = (const int*)d_in[1];
    const float* W1 = (const float*)d_in[3];
    const float* b1 = (const float*)d_in[4];
    const float* W2 = (const float*)d_in[5];
    const float* b2 = (const float*)d_in[6];
    const float* W3 = (const float*)d_in[7];
    const float* b3 = (const float*)d_in[8];
    const float* W4 = (const float*)d_in[9];
    const float* b4 = (const float*)d_in[10];
    float* out = (float*)d_out;

    // ws (4B slots): tstart[25088] tcnt[25088] btot[196] gpool[64]
    //   row[NN] rend[NN] csr[NE]
    //   then: pairs[NE ints] | z1b[NN*32 bf16 = NN*16 slots] | agg1[NN*32 f32]
    //         ^-- agg2[NN*64 f32] exactly overlays these three (all dead
    //             after k_mid; pairs dead after k_build)
    //   then: z2b[NN*64 bf16 = NN*32 slots]
    //   total ~46 MB
    int*   ip     = (int*)d_ws;
    int*   tstart = ip;                          // 25088
    int*   tcnt   = ip + NLB * NB;               // 25088
    int*   btot   = ip + 2 * NLB * NB;           // 196
    float* gpool  = (float*)(ip + 2 * NLB * NB + 196);  // 64
    int*   row    = ip + 2 * NLB * NB + 260;     // NN
    int*   rend   = row + NN;                    // NN
    int*   csr    = rend + NN;                   // NE
    int*   pairs  = csr + NE;                    // NE slots
    unsigned short* z1b = (unsigned short*)(pairs + NE);        // NN*32 bf16 (NN*16 slots)
    float* agg1   = (float*)(pairs + NE + NN * 16);             // NN*32 f32
    float* agg2   = (float*)pairs;               // NN*64 f32 == pairs+z1b+agg1 region
    unsigned short* z2b = (unsigned short*)(agg1 + (size_t)NN * 32);  // NN*64 bf16
    const int* src = ei;
    const int* dst = ei + NE;

    hipMemsetAsync(btot, 0, (196 + 64) * sizeof(int), stream);  // btot + gpool
    k_lsort<<<NLB, 256, 0, stream>>>(src, dst, pairs, tstart, tcnt, btot);
    k_build<<<NB, 1024, 0, stream>>>(pairs, tstart, tcnt, btot, csr, row, rend);
    k_lin1<<<1024, 256, 0, stream>>>(x, W1, z1b);
    k_gather32<<<NN / 8, 256, 0, stream>>>(row, rend, csr, z1b, agg1);
    k_mid<<<1024, 256, 0, stream>>>(z1b, agg1, b1, W2, b2, W3, z2b);
    k_gather64<<<NN / 4, 256, 0, stream>>>(row, rend, csr, z2b, agg2);
    k_final<<<1024, 256, 0, stream>>>(z2b, agg2, b3, W4, b4, out, gpool);
    k_pool<<<1, 64, 0, stream>>>(gpool, out);
}

// Round 10
// 326.657 us; speedup vs baseline: 3.7852x; 1.0796x over previous
//
#include <hip/hip_runtime.h>

#define NN 100000
#define NE 1600000
#define NLB 256            // lsort chunks (full-GPU block count)
#define CHUNK (NE / NLB)   // 6250 edges per chunk
#define NB 196             // dst buckets (dst >> 9), 196*512 >= NN
#define BN 512             // nodes per bucket

__device__ __forceinline__ float bf2f(unsigned short u) {
    return __uint_as_float(((unsigned int)u) << 16);
}
__device__ __forceinline__ unsigned short f2bf(float f) {
    unsigned int u = __float_as_uint(f);
    return (unsigned short)((u + 0x7FFFu + ((u >> 16) & 1u)) >> 16);
}

// ================= fused front end: blocks [0,NLB) sort edges, rest do z1=x@W1
// The two jobs are independent; branch is block-uniform so barriers are legal.
__global__ __launch_bounds__(256) void k_front(const int* __restrict__ src,
                                               const int* __restrict__ dst,
                                               int* __restrict__ pairs,
                                               int* __restrict__ tstart,
                                               int* __restrict__ tcnt,
                                               int* __restrict__ btot,
                                               const float* __restrict__ x,
                                               const float* __restrict__ W1,
                                               unsigned short* __restrict__ z1) {
    __shared__ float Ws[128 * 32];     // lin1 (16 KB)
    __shared__ float xs[32][129];      // lin1 (16.5 KB)
    __shared__ int cnt[NB];            // lsort
    __shared__ int sc[256];
    __shared__ int cur[NB];
    int tid = threadIdx.x;
    if (blockIdx.x < NLB) {
        // ---------------- bucket sort (validated R7-R9 logic, smaller chunks)
        int blk = blockIdx.x;
        int e0 = blk * CHUNK;
        for (int i = tid; i < NB; i += 256) cnt[i] = 0;
        __syncthreads();
        for (int i = tid; i < CHUNK; i += 256) atomicAdd(&cnt[dst[e0 + i] >> 9], 1);
        __syncthreads();
        sc[tid] = (tid < NB) ? cnt[tid] : 0;
        __syncthreads();
        for (int off = 1; off < 256; off <<= 1) {
            int v = (tid >= off) ? sc[tid - off] : 0;
            __syncthreads();
            sc[tid] += v;
            __syncthreads();
        }
        if (tid < NB) {
            int excl = sc[tid] - cnt[tid];
            cur[tid] = excl;
            tstart[blk * NB + tid] = excl;
            tcnt[blk * NB + tid]   = cnt[tid];
            atomicAdd(&btot[tid], cnt[tid]);
        }
        __syncthreads();
        for (int i = tid; i < CHUNK; i += 256) {
            int d = dst[e0 + i], s = src[e0 + i];
            int p = atomicAdd(&cur[d >> 9], 1);
            pairs[e0 + p] = ((d & (BN - 1)) << 17) | s;
        }
    } else {
        // ---------------- z1 = x @ W1, bf16 out (validated R9 logic)
        int bid = blockIdx.x - NLB;        // 0..1023
        for (int i = tid; i < 1024; i += 256) {
            float4 w = ((const float4*)W1)[i];
            float* d = &Ws[i * 4];
            d[0] = w.x; d[1] = w.y; d[2] = w.z; d[3] = w.w;
        }
        int n_loc = tid >> 3;
        int j0    = (tid & 7) * 4;
        for (int base = bid * 32; base < NN; base += 1024 * 32) {
            __syncthreads();
            for (int t = tid; t < 1024; t += 256) {
                int n = t >> 5, c = t & 31;
                float4 v = ((const float4*)(x + (size_t)(base + n) * 128))[c];
                float* d = &xs[n][c * 4];
                d[0] = v.x; d[1] = v.y; d[2] = v.z; d[3] = v.w;
            }
            __syncthreads();
            float a0 = 0.f, a1 = 0.f, a2 = 0.f, a3 = 0.f;
            #pragma unroll 8
            for (int k = 0; k < 128; k++) {
                float xv = xs[n_loc][k];
                float4 w = *(const float4*)&Ws[k * 32 + j0];
                a0 = fmaf(xv, w.x, a0); a1 = fmaf(xv, w.y, a1);
                a2 = fmaf(xv, w.z, a2); a3 = fmaf(xv, w.w, a3);
            }
            ushort4 o = { f2bf(a0), f2bf(a1), f2bf(a2), f2bf(a3) };
            *(ushort4*)&z1[(size_t)(base + n_loc) * 32 + j0] = o;
        }
    }
}

// ============================= pass 2: per-bucket CSR via wave segment-walks
// (validated R8/R9; NLB now 256 -> 16 segments per wave)
__global__ __launch_bounds__(1024) void k_build(const int* __restrict__ pairs,
                                                const int* __restrict__ tstart,
                                                const int* __restrict__ tcnt,
                                                const int* __restrict__ btot,
                                                int* __restrict__ csr,
                                                int* __restrict__ row,
                                                int* __restrict__ rend) {
    __shared__ int segS[NLB], segL[NLB];
    __shared__ int ncnt[BN];
    __shared__ int nbase[BN + 1];
    __shared__ int sc[256];
    __shared__ int sc2[256];
    __shared__ int base_s;
    int tid = threadIdx.x, b = blockIdx.x;

    if (tid < 256) sc2[tid] = (tid < NB) ? btot[tid] : 0;
    __syncthreads();
    for (int off = 1; off < 256; off <<= 1) {
        int v = 0;
        if (tid < 256 && tid >= off) v = sc2[tid - off];
        __syncthreads();
        if (tid < 256) sc2[tid] += v;
        __syncthreads();
    }
    if (tid == 0) base_s = (b == 0) ? 0 : sc2[b - 1];
    if (tid < NLB) {
        segS[tid] = tid * CHUNK + tstart[tid * NB + b];
        segL[tid] = tcnt[tid * NB + b];
    }
    for (int i = tid; i < BN; i += 1024) ncnt[i] = 0;
    __syncthreads();

    int wave = tid >> 6, lane = tid & 63;
    for (int s = wave; s < NLB; s += 16) {
        int st = segS[s], len = segL[s];
        for (int i = lane; i < len; i += 64)
            atomicAdd(&ncnt[pairs[st + i] >> 17], 1);
    }
    __syncthreads();

    int c0 = 0, c1 = 0, tsum = 0;
    if (tid < 256) { c0 = ncnt[2 * tid]; c1 = ncnt[2 * tid + 1]; tsum = c0 + c1; sc[tid] = tsum; }
    __syncthreads();
    for (int off = 1; off < 256; off <<= 1) {
        int v = 0;
        if (tid < 256 && tid >= off) v = sc[tid - off];
        __syncthreads();
        if (tid < 256) sc[tid] += v;
        __syncthreads();
    }
    if (tid < 256) {
        int excl = sc[tid] - tsum;
        nbase[2 * tid]     = excl;
        nbase[2 * tid + 1] = excl + c0;
        if (tid == 255) nbase[BN] = sc[255];
    }
    __syncthreads();

    int base = base_s;
    if (tid < BN) {
        int n = b * BN + tid;
        if (n < NN) { row[n] = base + nbase[tid]; rend[n] = base + nbase[tid + 1]; }
        ncnt[tid] = 0;
    }
    __syncthreads();

    for (int s = wave; s < NLB; s += 16) {
        int st = segS[s], len = segL[s];
        for (int i = lane; i < len; i += 64) {
            int p = pairs[st + i];
            int ln = p >> 17;
            int pos = atomicAdd(&ncnt[ln], 1);
            csr[base + nbase[ln] + pos] = p & 0x1FFFF;
        }
    }
}

// ================================================================ gathers
__global__ __launch_bounds__(256) void k_gather32(const int* __restrict__ row,
                                                  const int* __restrict__ rend,
                                                  const int* __restrict__ csr,
                                                  const unsigned short* __restrict__ z,
                                                  float* __restrict__ agg) {
    int n = blockIdx.x * 8 + (threadIdx.x >> 5);
    int f = threadIdx.x & 31;
    int j = row[n], e = rend[n];
    float a0 = 0.f, a1 = 0.f, a2 = 0.f, a3 = 0.f;
    for (; j + 3 < e; j += 4) {
        int i0 = csr[j], i1 = csr[j + 1], i2 = csr[j + 2], i3 = csr[j + 3];
        a0 += bf2f(z[(size_t)i0 * 32 + f]);
        a1 += bf2f(z[(size_t)i1 * 32 + f]);
        a2 += bf2f(z[(size_t)i2 * 32 + f]);
        a3 += bf2f(z[(size_t)i3 * 32 + f]);
    }
    for (; j < e; j++) a0 += bf2f(z[(size_t)csr[j] * 32 + f]);
    agg[(size_t)n * 32 + f] = (a0 + a1) + (a2 + a3);
}

// unroll 8: deeper MLP against L2-miss latency
__global__ __launch_bounds__(256) void k_gather64(const int* __restrict__ row,
                                                  const int* __restrict__ rend,
                                                  const int* __restrict__ csr,
                                                  const unsigned short* __restrict__ z,
                                                  float* __restrict__ agg) {
    int n = blockIdx.x * 4 + (threadIdx.x >> 6);
    int f = threadIdx.x & 63;
    int j = row[n], e = rend[n];
    float a0 = 0.f, a1 = 0.f, a2 = 0.f, a3 = 0.f;
    for (; j + 7 < e; j += 8) {
        int i0 = csr[j],     i1 = csr[j + 1], i2 = csr[j + 2], i3 = csr[j + 3];
        int i4 = csr[j + 4], i5 = csr[j + 5], i6 = csr[j + 6], i7 = csr[j + 7];
        float v0 = bf2f(z[(size_t)i0 * 64 + f]);
        float v1 = bf2f(z[(size_t)i1 * 64 + f]);
        float v2 = bf2f(z[(size_t)i2 * 64 + f]);
        float v3 = bf2f(z[(size_t)i3 * 64 + f]);
        float v4 = bf2f(z[(size_t)i4 * 64 + f]);
        float v5 = bf2f(z[(size_t)i5 * 64 + f]);
        float v6 = bf2f(z[(size_t)i6 * 64 + f]);
        float v7 = bf2f(z[(size_t)i7 * 64 + f]);
        a0 += v0 + v4; a1 += v1 + v5; a2 += v2 + v6; a3 += v3 + v7;
    }
    for (; j + 3 < e; j += 4) {
        int i0 = csr[j], i1 = csr[j + 1], i2 = csr[j + 2], i3 = csr[j + 3];
        a0 += bf2f(z[(size_t)i0 * 64 + f]);
        a1 += bf2f(z[(size_t)i1 * 64 + f]);
        a2 += bf2f(z[(size_t)i2 * 64 + f]);
        a3 += bf2f(z[(size_t)i3 * 64 + f]);
    }
    for (; j < e; j++) a0 += bf2f(z[(size_t)csr[j] * 64 + f]);
    agg[(size_t)n * 64 + f] = (a0 + a1) + (a2 + a3);
}

// --- fused: t = relu(z1+agg1+b1); h = relu(t@W2+b2); z2 = h@W3 (bf16 in/out)
__global__ __launch_bounds__(256) void k_mid(const unsigned short* __restrict__ z1,
                                             const float* __restrict__ agg1,
                                             const float* __restrict__ b1,
                                             const float* __restrict__ W2,
                                             const float* __restrict__ b2,
                                             const float* __restrict__ W3,
                                             unsigned short* __restrict__ z2) {
    __shared__ float W2s[32 * 64];
    __shared__ float W3s[64 * 64];
    __shared__ float ts[32][33];
    __shared__ float hs[32 * 68];
    __shared__ float b1s[32], b2s[64];
    for (int i = threadIdx.x; i < 512; i += 256) {
        float4 w = ((const float4*)W2)[i];
        float* d = &W2s[i * 4];
        d[0] = w.x; d[1] = w.y; d[2] = w.z; d[3] = w.w;
    }
    for (int i = threadIdx.x; i < 1024; i += 256) {
        float4 w = ((const float4*)W3)[i];
        float* d = &W3s[i * 4];
        d[0] = w.x; d[1] = w.y; d[2] = w.z; d[3] = w.w;
    }
    if (threadIdx.x < 32) b1s[threadIdx.x] = b1[threadIdx.x];
    if (threadIdx.x >= 64 && threadIdx.x < 128) b2s[threadIdx.x - 64] = b2[threadIdx.x - 64];
    int n2 = threadIdx.x >> 4;
    int j0 = (threadIdx.x & 15) * 4;
    int na = 2 * n2, nb = 2 * n2 + 1;
    for (int base = blockIdx.x * 32; base < NN; base += gridDim.x * 32) {
        __syncthreads();
        #pragma unroll
        for (int r = 0; r < 4; r++) {
            int idx = threadIdx.x + 256 * r;
            int n = idx >> 5, f = idx & 31;
            ts[n][f] = fmaxf(bf2f(z1[(size_t)base * 32 + idx]) + agg1[(size_t)base * 32 + idx] + b1s[f], 0.f);
        }
        __syncthreads();
        {
            float a00=0,a01=0,a02=0,a03=0,a10=0,a11=0,a12=0,a13=0;
            #pragma unroll 8
            for (int k = 0; k < 32; k++) {
                float t0 = ts[na][k], t1 = ts[nb][k];
                float4 w = *(const float4*)&W2s[k * 64 + j0];
                a00=fmaf(t0,w.x,a00); a01=fmaf(t0,w.y,a01); a02=fmaf(t0,w.z,a02); a03=fmaf(t0,w.w,a03);
                a10=fmaf(t1,w.x,a10); a11=fmaf(t1,w.y,a11); a12=fmaf(t1,w.z,a12); a13=fmaf(t1,w.w,a13);
            }
            *(float4*)&hs[na * 68 + j0] = make_float4(fmaxf(a00+b2s[j0],0.f), fmaxf(a01+b2s[j0+1],0.f),
                                                      fmaxf(a02+b2s[j0+2],0.f), fmaxf(a03+b2s[j0+3],0.f));
            *(float4*)&hs[nb * 68 + j0] = make_float4(fmaxf(a10+b2s[j0],0.f), fmaxf(a11+b2s[j0+1],0.f),
                                                      fmaxf(a12+b2s[j0+2],0.f), fmaxf(a13+b2s[j0+3],0.f));
        }
        __syncthreads();
        {
            float a00=0,a01=0,a02=0,a03=0,a10=0,a11=0,a12=0,a13=0;
            #pragma unroll 8
            for (int k = 0; k < 64; k++) {
                float h0 = hs[na * 68 + k], h1 = hs[nb * 68 + k];
                float4 w = *(const float4*)&W3s[k * 64 + j0];
                a00=fmaf(h0,w.x,a00); a01=fmaf(h0,w.y,a01); a02=fmaf(h0,w.z,a02); a03=fmaf(h0,w.w,a03);
                a10=fmaf(h1,w.x,a10); a11=fmaf(h1,w.y,a11); a12=fmaf(h1,w.z,a12); a13=fmaf(h1,w.w,a13);
            }
            ushort4 oa = { f2bf(a00), f2bf(a01), f2bf(a02), f2bf(a03) };
            ushort4 ob = { f2bf(a10), f2bf(a11), f2bf(a12), f2bf(a13) };
            *(ushort4*)&z2[(size_t)(base + na) * 64 + j0] = oa;
            *(ushort4*)&z2[(size_t)(base + nb) * 64 + j0] = ob;
        }
    }
}

// --------- final: u = relu(z2+agg2+b3); out = relu(u@W4+b4) -> f32 + pooled
__global__ __launch_bounds__(256) void k_final(const unsigned short* __restrict__ z2,
                                               const float* __restrict__ agg2,
                                               const float* __restrict__ b3,
                                               const float* __restrict__ W4,
                                               const float* __restrict__ b4,
                                               float* __restrict__ out,
                                               float* __restrict__ gpool) {
    __shared__ float W4s[64 * 64];
    __shared__ float us[32 * 68];
    __shared__ float b3s[64], b4s[64], pool[64];
    for (int i = threadIdx.x; i < 1024; i += 256) {
        float4 w = ((const float4*)W4)[i];
        float* d = &W4s[i * 4];
        d[0] = w.x; d[1] = w.y; d[2] = w.z; d[3] = w.w;
    }
    if (threadIdx.x < 64) { b3s[threadIdx.x] = b3[threadIdx.x]; pool[threadIdx.x] = 0.f; }
    if (threadIdx.x >= 64 && threadIdx.x < 128) b4s[threadIdx.x - 64] = b4[threadIdx.x - 64];
    int n2 = threadIdx.x >> 4;
    int j0 = (threadIdx.x & 15) * 4;
    int na = 2 * n2, nb = 2 * n2 + 1;
    float p0 = 0.f, p1 = 0.f, p2 = 0.f, p3 = 0.f;
    for (int base = blockIdx.x * 32; base < NN; base += gridDim.x * 32) {
        __syncthreads();
        #pragma unroll
        for (int r = 0; r < 8; r++) {
            int idx = threadIdx.x + 256 * r;
            int n = idx >> 6, f = idx & 63;
            us[n * 68 + f] = fmaxf(bf2f(z2[(size_t)base * 64 + idx]) + agg2[(size_t)base * 64 + idx] + b3s[f], 0.f);
        }
        __syncthreads();
        float a00=0,a01=0,a02=0,a03=0,a10=0,a11=0,a12=0,a13=0;
        #pragma unroll 8
        for (int k = 0; k < 64; k++) {
            float u0 = us[na * 68 + k], u1 = us[nb * 68 + k];
            float4 w = *(const float4*)&W4s[k * 64 + j0];
            a00=fmaf(u0,w.x,a00); a01=fmaf(u0,w.y,a01); a02=fmaf(u0,w.z,a02); a03=fmaf(u0,w.w,a03);
            a10=fmaf(u1,w.x,a10); a11=fmaf(u1,w.y,a11); a12=fmaf(u1,w.z,a12); a13=fmaf(u1,w.w,a13);
        }
        float v00=fmaxf(a00+b4s[j0],0.f), v01=fmaxf(a01+b4s[j0+1],0.f);
        float v02=fmaxf(a02+b4s[j0+2],0.f), v03=fmaxf(a03+b4s[j0+3],0.f);
        float v10=fmaxf(a10+b4s[j0],0.f), v11=fmaxf(a11+b4s[j0+1],0.f);
        float v12=fmaxf(a12+b4s[j0+2],0.f), v13=fmaxf(a13+b4s[j0+3],0.f);
        *(float4*)&out[(size_t)(base + na) * 64 + j0] = make_float4(v00, v01, v02, v03);
        *(float4*)&out[(size_t)(base + nb) * 64 + j0] = make_float4(v10, v11, v12, v13);
        p0 += v00 + v10; p1 += v01 + v11; p2 += v02 + v12; p3 += v03 + v13;
    }
    __syncthreads();
    atomicAdd(&pool[j0 + 0], p0);
    atomicAdd(&pool[j0 + 1], p1);
    atomicAdd(&pool[j0 + 2], p2);
    atomicAdd(&pool[j0 + 3], p3);
    __syncthreads();
    if (threadIdx.x < 64) unsafeAtomicAdd(&gpool[threadIdx.x], pool[threadIdx.x]);
}

__global__ void k_pool(const float* __restrict__ gpool, float* __restrict__ out) {
    int t = threadIdx.x;
    if (t < 64) out[(size_t)NN * 64 + t] = gpool[t] * (1.0f / NN);
}

extern "C" void kernel_launch(void* const* d_in, const int* in_sizes, int n_in,
                              void* d_out, int out_size, void* d_ws, size_t ws_size,
                              hipStream_t stream) {
    const float* x  = (const float*)d_in[0];
    const int*   ei = (const int*)d_in[1];
    const float* W1 = (const float*)d_in[3];
    const float* b1 = (const float*)d_in[4];
    const float* W2 = (const float*)d_in[5];
    const float* b2 = (const float*)d_in[6];
    const float* W3 = (const float*)d_in[7];
    const float* b3 = (const float*)d_in[8];
    const float* W4 = (const float*)d_in[9];
    const float* b4 = (const float*)d_in[10];
    float* out = (float*)d_out;

    // ws (4B slots): tstart[NLB*NB] tcnt[NLB*NB] btot[196] gpool[64]
    //   row[NN] rend[NN] csr[NE]
    //   then: pairs[NE] | z1b[NN*16] | agg1[NN*32]   (sum = NN*64 slots)
    //         ^-- agg2[NN*64 f32] exactly overlays these three
    //   then: z2b[NN*32 slots].   total ~46 MB
    int*   ip     = (int*)d_ws;
    int*   tstart = ip;                          // NLB*NB = 50176
    int*   tcnt   = ip + NLB * NB;               // 50176
    int*   btot   = ip + 2 * NLB * NB;           // 196
    float* gpool  = (float*)(ip + 2 * NLB * NB + 196);  // 64
    int*   row    = ip + 2 * NLB * NB + 260;     // NN
    int*   rend   = row + NN;                    // NN
    int*   csr    = rend + NN;                   // NE
    int*   pairs  = csr + NE;                    // NE
    unsigned short* z1b = (unsigned short*)(pairs + NE);        // NN*32 bf16
    float* agg1   = (float*)(pairs + NE + NN * 16);             // NN*32 f32
    float* agg2   = (float*)pairs;               // overlays pairs+z1b+agg1
    unsigned short* z2b = (unsigned short*)(agg1 + (size_t)NN * 32);  // NN*64 bf16
    const int* src = ei;
    const int* dst = ei + NE;

    hipMemsetAsync(btot, 0, (196 + 64) * sizeof(int), stream);  // btot + gpool
    k_front<<<NLB + 1024, 256, 0, stream>>>(src, dst, pairs, tstart, tcnt, btot, x, W1, z1b);
    k_build<<<NB, 1024, 0, stream>>>(pairs, tstart, tcnt, btot, csr, row, rend);
    k_gather32<<<NN / 8, 256, 0, stream>>>(row, rend, csr, z1b, agg1);
    k_mid<<<1024, 256, 0, stream>>>(z1b, agg1, b1, W2, b2, W3, z2b);
    k_gather64<<<NN / 4, 256, 0, stream>>>(row, rend, csr, z2b, agg2);
    k_final<<<1024, 256, 0, stream>>>(z2b, agg2, b3, W4, b4, out, gpool);
    k_pool<<<1, 64, 0, stream>>>(gpool, out);
}